// Round 7
// baseline (314.077 us; speedup 1.0000x reference)
//
#include <hip/hip_runtime.h>
#include <stdint.h>

#define M_TOT 8192
#define N_TOT 4096
#define K_TOT 4096
#define BM 256
#define BN 256
#define BK 64
#define NIT (K_TOT / (2 * BK))   // 32 iters, 2 K-tiles each

typedef short  s16x8 __attribute__((ext_vector_type(8)));
typedef unsigned short u16x8 __attribute__((ext_vector_type(8)));
typedef float  f32x4 __attribute__((ext_vector_type(4)));

__device__ __forceinline__ unsigned short f32_to_bf16(float f) {
  union { float f; unsigned u; } v; v.f = f;
  unsigned r = v.u + 0x7FFFu + ((v.u >> 16) & 1u);   // RNE
  return (unsigned short)(r >> 16);
}

__device__ __forceinline__ void gload_lds16(void* lds, const void* g) {
  __builtin_amdgcn_global_load_lds(
      (const __attribute__((address_space(1))) unsigned int*)g,
      (__attribute__((address_space(3))) unsigned int*)lds,
      16, 0, 0);
}

// ---- Prep 1: partial column sums of squares of (weight + tiled mora) ----
__global__ void colnorm_partial_k(const float* __restrict__ weight,
                                  const float* __restrict__ mora,
                                  float* __restrict__ partials) {
  int d = blockIdx.x * 256 + threadIdx.x;
  int o0 = blockIdx.y * 128;
  float s = 0.f;
  #pragma unroll 4
  for (int o = o0; o < o0 + 128; ++o) {
    float w = weight[(size_t)o * K_TOT + d] + mora[(size_t)(o >> 1) * 2048 + (d >> 1)];
    s = fmaf(w, w, s);
  }
  partials[blockIdx.y * K_TOT + d] = s;
}

// ---- Prep 2: scale[d] = dora_mag[d] / sqrt(sum) ----
__global__ void scale_k(const float* __restrict__ partials,
                        const float* __restrict__ dora_mag,
                        float* __restrict__ scale) {
  int d = blockIdx.x * 256 + threadIdx.x;
  float s = 0.f;
  #pragma unroll
  for (int c = 0; c < 32; ++c) s += partials[c * K_TOT + d];
  scale[d] = dora_mag[d] / sqrtf(s);
}

// ---- Prep 3: w_bf16[o][d] = bf16((weight + mora_tiled) * scale[d]) ----
__global__ void pack_w_k(const float* __restrict__ weight,
                         const float* __restrict__ mora,
                         const float* __restrict__ scale,
                         unsigned short* __restrict__ wb) {
  size_t idx = ((size_t)blockIdx.x * 256 + threadIdx.x) * 8;
  int o = (int)(idx >> 12);
  int d = (int)(idx & (K_TOT - 1));
  float4 w0 = *(const float4*)(weight + idx);
  float4 w1 = *(const float4*)(weight + idx + 4);
  float4 mv = *(const float4*)(mora + (size_t)(o >> 1) * 2048 + (d >> 1));
  float4 s0 = *(const float4*)(scale + d);
  float4 s1 = *(const float4*)(scale + d + 4);
  u16x8 r;
  r[0] = f32_to_bf16((w0.x + mv.x) * s0.x);
  r[1] = f32_to_bf16((w0.y + mv.x) * s0.y);
  r[2] = f32_to_bf16((w0.z + mv.y) * s0.z);
  r[3] = f32_to_bf16((w0.w + mv.y) * s0.w);
  r[4] = f32_to_bf16((w1.x + mv.z) * s1.x);
  r[5] = f32_to_bf16((w1.y + mv.z) * s1.y);
  r[6] = f32_to_bf16((w1.z + mv.w) * s1.z);
  r[7] = f32_to_bf16((w1.w + mv.w) * s1.w);
  *(u16x8*)(wb + idx) = r;
}

// ---- Prep 4: x -> bf16 ----
__global__ void pack_x_k(const float* __restrict__ x, unsigned short* __restrict__ xb) {
  size_t idx = ((size_t)blockIdx.x * 256 + threadIdx.x) * 8;
  float4 v0 = *(const float4*)(x + idx);
  float4 v1 = *(const float4*)(x + idx + 4);
  u16x8 r;
  r[0] = f32_to_bf16(v0.x); r[1] = f32_to_bf16(v0.y);
  r[2] = f32_to_bf16(v0.z); r[3] = f32_to_bf16(v0.w);
  r[4] = f32_to_bf16(v1.x); r[5] = f32_to_bf16(v1.y);
  r[6] = f32_to_bf16(v1.z); r[7] = f32_to_bf16(v1.w);
  *(u16x8*)(xb + idx) = r;
}

// ---- Main GEMM: 8-phase m201 template, R7 revision: stages moved to the
// phase right after their LDS region's last reader (B at ph3/ph7, A at
// ph4/ph8) -> 4-5 phase stage->gate lead (clears ~900cyc HBM latency),
// vmcnt(8) gates (4 half-tiles in flight, never drained below 8 in loop).
// WAR: region's readers drain at their phase's lgkmcnt(0), all waves by
// that phase's post-MFMA barrier, stage issued after it. ----
__global__ void __launch_bounds__(512, 2) gemm_bf16_k(
    const unsigned short* __restrict__ xb,   // [8192][4096]
    const unsigned short* __restrict__ wb,   // [4096][4096]
    float* __restrict__ out) {               // [8192][4096]
  // [buf][op A=0/B=1][half][128*64] = 8 x 16KB = 128KB
  __shared__ short lds[2][2][2][128 * 64];

  const int tid = threadIdx.x;
  const int l   = tid & 63;
  const int wid = tid >> 6;
  const int wm  = wid >> 2;                  // 0..1 -> A half / M rows wm*128
  const int wn  = wid & 3;                   // 0..3 -> N cols wn*64
  const int wnh = wn >> 1;                   // B half

  // XCD-aware bijective swizzle (nwg=512, divisible by 8)
  const int orig = blockIdx.x;
  const int swz  = (orig & 7) * (512 >> 3) + (orig >> 3);
  const int by = swz >> 4;                   // 0..31
  const int bx = swz & 15;                   // 0..15

  const unsigned short* ag = xb + (size_t)(by * BM) * K_TOT;
  const unsigned short* bg = wb + (size_t)(bx * BN) * K_TOT;

  // Staging: half-tile = 128 rows x 64 cols (16KB) = 1024 chunks of 16B;
  // thread handles chunks tid and tid+512. LDS dest linear (chunk c -> c*16B);
  // global source pre-swizzled: kblk_src = (c&7) ^ ((c>>3)&7).
  const int row0 = tid >> 3;
  const int kb0  = (tid & 7) ^ (row0 & 7);
  const int off0 = row0 * K_TOT + kb0 * 8;
  const int off1 = off0 + 64 * K_TOT;
  const int ldst = (tid & ~63) * 8;          // wave-uniform LDS base (shorts)

  // Fragment reads: phys kblk = (kh*4 + lq) ^ (lrow&7)
  const int lrow = l & 15;
  const int lq   = l >> 4;
  const int key  = lrow & 7;
  const int ab0  = lrow * 64 + ((lq) ^ key) * 8;        // kh=0
  const int ab1  = lrow * 64 + ((4 + lq) ^ key) * 8;    // kh=1

  s16x8 aA[4][2], bB[4][2];
  f32x4 acc[8][4] = {};

#define STAGE(buf, op, h, t) { \
    short* d = &lds[buf][op][h][0] + ldst; \
    const unsigned short* s = ((op) ? bg : ag) + (size_t)(h) * 128 * K_TOT + (size_t)(t) * BK; \
    gload_lds16(d, s + off0); \
    gload_lds16(d + 4096, s + off1); }
#define DSA(buf, mh) { const short* p = &lds[buf][0][wm][0]; \
    _Pragma("unroll") for (int mm = 0; mm < 4; ++mm) { \
      aA[mm][0] = *(const s16x8*)(p + ((mh) * 4 + mm) * 1024 + ab0); \
      aA[mm][1] = *(const s16x8*)(p + ((mh) * 4 + mm) * 1024 + ab1); } }
#define DSB(buf, nh) { const short* p = &lds[buf][1][wnh][0] + (wn & 1) * 4096; \
    _Pragma("unroll") for (int nn = 0; nn < 2; ++nn) { \
      bB[(nh) * 2 + nn][0] = *(const s16x8*)(p + ((nh) * 2 + nn) * 1024 + ab0); \
      bB[(nh) * 2 + nn][1] = *(const s16x8*)(p + ((nh) * 2 + nn) * 1024 + ab1); } }
#define MMQ(mh, nh) { __builtin_amdgcn_s_setprio(1); \
    _Pragma("unroll") for (int mm = 0; mm < 4; ++mm) \
      _Pragma("unroll") for (int nn = 0; nn < 2; ++nn) \
        _Pragma("unroll") for (int kh = 0; kh < 2; ++kh) \
          acc[(mh) * 4 + mm][(nh) * 2 + nn] = __builtin_amdgcn_mfma_f32_16x16x32_bf16( \
              aA[mm][kh], bB[(nh) * 2 + nn][kh], acc[(mh) * 4 + mm][(nh) * 2 + nn], 0, 0, 0); \
    __builtin_amdgcn_s_setprio(0); }
#define BARm()  asm volatile("s_barrier" ::: "memory")
#define LGKM0() asm volatile("s_waitcnt lgkmcnt(0)" ::: "memory")
#define VM8()   asm volatile("s_waitcnt vmcnt(8)" ::: "memory")
#define VM0()   asm volatile("s_waitcnt vmcnt(0)" ::: "memory")
#define SB0()   __builtin_amdgcn_sched_barrier(0)

  // prologue: stage tile0 (buf0, 8 loads) then tile1 (buf1, 8 loads)
  STAGE(0, 0, 0, 0); STAGE(0, 0, 1, 0); STAGE(0, 1, 0, 0); STAGE(0, 1, 1, 0);
  STAGE(1, 0, 0, 1); STAGE(1, 0, 1, 1); STAGE(1, 1, 0, 1); STAGE(1, 1, 1, 1);
  VM8(); BARm();                             // buf0 complete; buf1 in flight

  #pragma unroll 1
  for (int i = 0; i < NIT - 1; ++i) {
    const int t0 = 2 * i;
    // ph1: buf0 quad(0,0)
    DSA(0, 0); DSB(0, 0);
    BARm(); LGKM0(); SB0(); MMQ(0, 0); BARm();
    // ph2: buf0 quad(0,1)  [last reader of buf0-B]
    DSB(0, 1);
    BARm(); LGKM0(); SB0(); MMQ(0, 1); BARm();
    // ph3: buf0 quad(1,0) [last reader of buf0-A]; stage buf0-next B
    DSA(0, 1);
    STAGE(0, 1, 0, t0 + 2); STAGE(0, 1, 1, t0 + 2);
    BARm(); LGKM0(); SB0(); MMQ(1, 0); BARm();
    // ph4: buf0 quad(1,1); stage buf0-next A; gate buf1 (tile t0+1)
    STAGE(0, 0, 0, t0 + 2); STAGE(0, 0, 1, t0 + 2);
    BARm(); LGKM0(); SB0(); MMQ(1, 1); VM8(); BARm();
    // ph5: buf1 quad(0,0)
    DSA(1, 0); DSB(1, 0);
    BARm(); LGKM0(); SB0(); MMQ(0, 0); BARm();
    // ph6: buf1 quad(0,1)  [last reader of buf1-B]
    DSB(1, 1);
    BARm(); LGKM0(); SB0(); MMQ(0, 1); BARm();
    // ph7: buf1 quad(1,0) [last reader of buf1-A]; stage buf1-next B
    DSA(1, 1);
    STAGE(1, 1, 0, t0 + 3); STAGE(1, 1, 1, t0 + 3);
    BARm(); LGKM0(); SB0(); MMQ(1, 0); BARm();
    // ph8: buf1 quad(1,1); stage buf1-next A; gate buf0-next (tile t0+2)
    STAGE(1, 0, 0, t0 + 3); STAGE(1, 0, 1, t0 + 3);
    BARm(); LGKM0(); SB0(); MMQ(1, 1); VM8(); BARm();
  }

  // peeled last iter (tiles 62,63): no staging
  DSA(0, 0); DSB(0, 0);
  BARm(); LGKM0(); SB0(); MMQ(0, 0); BARm();
  DSB(0, 1);
  BARm(); LGKM0(); SB0(); MMQ(0, 1); BARm();
  DSA(0, 1);
  BARm(); LGKM0(); SB0(); MMQ(1, 0); BARm();
  BARm(); LGKM0(); SB0(); MMQ(1, 1); VM0(); BARm();   // drain buf1-63
  DSA(1, 0); DSB(1, 0);
  BARm(); LGKM0(); SB0(); MMQ(0, 0); BARm();
  DSB(1, 1);
  BARm(); LGKM0(); SB0(); MMQ(0, 1); BARm();
  DSA(1, 1);
  BARm(); LGKM0(); SB0(); MMQ(1, 0); BARm();
  LGKM0(); SB0(); MMQ(1, 1);

#undef STAGE
#undef DSA
#undef DSB
#undef MMQ

  // C/D layout (verified R1-R6): col = lane&15, row = (lane>>4)*4 + reg
  const int row0o = by * BM + wm * 128 + lq * 4;
  const int col0o = bx * BN + wn * 64 + lrow;
  #pragma unroll
  for (int m = 0; m < 8; ++m)
    #pragma unroll
    for (int n = 0; n < 4; ++n) {
      #pragma unroll
      for (int j = 0; j < 4; ++j)
        out[(size_t)(row0o + m * 16 + j) * N_TOT + col0o + n * 16] = acc[m][n][j];
    }
}

// ---- Fallback fp32 GEMM (only if ws too small for bf16 copies) ----
__global__ void gemm_fb_k(const float* __restrict__ x, const float* __restrict__ weight,
                          const float* __restrict__ mora, const float* __restrict__ scale,
                          float* __restrict__ out) {
  __shared__ float As[64][17];
  __shared__ float Bs[64][17];
  int t = threadIdx.x;
  int bx = blockIdx.x, by = blockIdx.y;
  int tr = t >> 4, tc = t & 15;
  float c[4][4] = {};
  for (int kt = 0; kt < K_TOT; kt += 16) {
    #pragma unroll
    for (int r = 0; r < 4; ++r) {
      int idx = r * 256 + t;
      int row = idx >> 4, col = idx & 15;
      As[row][col] = x[(size_t)(by * 64 + row) * K_TOT + kt + col];
      int o = bx * 64 + row, d = kt + col;
      Bs[row][col] = (weight[(size_t)o * K_TOT + d] + mora[(size_t)(o >> 1) * 2048 + (d >> 1)]) * scale[d];
    }
    __syncthreads();
    #pragma unroll
    for (int k = 0; k < 16; ++k) {
      float av[4], bv[4];
      #pragma unroll
      for (int i = 0; i < 4; ++i) av[i] = As[tr * 4 + i][k];
      #pragma unroll
      for (int j = 0; j < 4; ++j) bv[j] = Bs[tc * 4 + j][k];
      #pragma unroll
      for (int i = 0; i < 4; ++i)
        #pragma unroll
        for (int j = 0; j < 4; ++j)
          c[i][j] = fmaf(av[i], bv[j], c[i][j]);
    }
    __syncthreads();
  }
  #pragma unroll
  for (int i = 0; i < 4; ++i)
    #pragma unroll
    for (int j = 0; j < 4; ++j)
      out[(size_t)(by * 64 + tr * 4 + i) * N_TOT + bx * 64 + tc * 4 + j] = c[i][j];
}

extern "C" void kernel_launch(void* const* d_in, const int* in_sizes, int n_in,
                              void* d_out, int out_size, void* d_ws, size_t ws_size,
                              hipStream_t stream) {
  const float* x      = (const float*)d_in[0];   // (4,2048,4096) f32
  const float* weight = (const float*)d_in[1];   // (4096,4096)   f32
  const float* mora   = (const float*)d_in[2];   // (2048,2048)   f32
  const float* dora   = (const float*)d_in[3];   // (1,4096)      f32
  float* out = (float*)d_out;                    // (4,2048,4096) f32

  char* ws = (char*)d_ws;
  float* partials = (float*)ws;                         // 512 KB
  float* scale    = (float*)(ws + (512 << 10));         // 16 KB
  const size_t OFF_W = (size_t)1 << 20;
  unsigned short* wbuf = (unsigned short*)(ws + OFF_W);                              // 32 MB
  unsigned short* xbuf = (unsigned short*)(ws + OFF_W + (size_t)N_TOT * K_TOT * 2);  // 64 MB
  const size_t NEED = OFF_W + (size_t)N_TOT * K_TOT * 2 + (size_t)M_TOT * K_TOT * 2;

  dim3 b256(256);
  colnorm_partial_k<<<dim3(16, 32), b256, 0, stream>>>(weight, mora, partials);
  scale_k<<<16, b256, 0, stream>>>(partials, dora, scale);

  if (ws_size >= NEED) {
    pack_w_k<<<(N_TOT * K_TOT) / (256 * 8), b256, 0, stream>>>(weight, mora, scale, wbuf);
    pack_x_k<<<(M_TOT * K_TOT) / (256 * 8), b256, 0, stream>>>(x, xbuf);
    gemm_bf16_k<<<(M_TOT / BM) * (N_TOT / BN), 512, 0, stream>>>(xbuf, wbuf, out);
  } else {
    gemm_fb_k<<<dim3(N_TOT / 64, M_TOT / 64), b256, 0, stream>>>(x, weight, mora, scale, out);
  }
}

// Round 9
// 303.067 us; speedup vs baseline: 1.0363x; 1.0363x over previous
//
#include <hip/hip_runtime.h>
#include <stdint.h>

#define M_TOT 8192
#define N_TOT 4096
#define K_TOT 4096
#define BM 256
#define BN 256
#define BK 64
#define NIT (K_TOT / (2 * BK))   // 32 iters, 2 K-tiles each

typedef short  s16x8 __attribute__((ext_vector_type(8)));
typedef unsigned short u16x8 __attribute__((ext_vector_type(8)));
typedef float  f32x4 __attribute__((ext_vector_type(4)));

__device__ __forceinline__ unsigned short f32_to_bf16(float f) {
  union { float f; unsigned u; } v; v.f = f;
  unsigned r = v.u + 0x7FFFu + ((v.u >> 16) & 1u);   // RNE
  return (unsigned short)(r >> 16);
}

__device__ __forceinline__ void gload_lds16(void* lds, const void* g) {
  __builtin_amdgcn_global_load_lds(
      (const __attribute__((address_space(1))) unsigned int*)g,
      (__attribute__((address_space(3))) unsigned int*)lds,
      16, 0, 0);
}

// ---- Prep 1: partial column sums of squares of (weight + tiled mora) ----
__global__ void colnorm_partial_k(const float* __restrict__ weight,
                                  const float* __restrict__ mora,
                                  float* __restrict__ partials) {
  int d = blockIdx.x * 256 + threadIdx.x;
  int o0 = blockIdx.y * 128;
  float s = 0.f;
  #pragma unroll 4
  for (int o = o0; o < o0 + 128; ++o) {
    float w = weight[(size_t)o * K_TOT + d] + mora[(size_t)(o >> 1) * 2048 + (d >> 1)];
    s = fmaf(w, w, s);
  }
  partials[blockIdx.y * K_TOT + d] = s;
}

// ---- Prep 2: scale[d] = dora_mag[d] / sqrt(sum) ----
__global__ void scale_k(const float* __restrict__ partials,
                        const float* __restrict__ dora_mag,
                        float* __restrict__ scale) {
  int d = blockIdx.x * 256 + threadIdx.x;
  float s = 0.f;
  #pragma unroll
  for (int c = 0; c < 32; ++c) s += partials[c * K_TOT + d];
  scale[d] = dora_mag[d] / sqrtf(s);
}

// ---- Prep 3: w_bf16[o][d] = bf16((weight + mora_tiled) * scale[d]) ----
__global__ void pack_w_k(const float* __restrict__ weight,
                         const float* __restrict__ mora,
                         const float* __restrict__ scale,
                         unsigned short* __restrict__ wb) {
  size_t idx = ((size_t)blockIdx.x * 256 + threadIdx.x) * 8;
  int o = (int)(idx >> 12);
  int d = (int)(idx & (K_TOT - 1));
  float4 w0 = *(const float4*)(weight + idx);
  float4 w1 = *(const float4*)(weight + idx + 4);
  float4 mv = *(const float4*)(mora + (size_t)(o >> 1) * 2048 + (d >> 1));
  float4 s0 = *(const float4*)(scale + d);
  float4 s1 = *(const float4*)(scale + d + 4);
  u16x8 r;
  r[0] = f32_to_bf16((w0.x + mv.x) * s0.x);
  r[1] = f32_to_bf16((w0.y + mv.x) * s0.y);
  r[2] = f32_to_bf16((w0.z + mv.y) * s0.z);
  r[3] = f32_to_bf16((w0.w + mv.y) * s0.w);
  r[4] = f32_to_bf16((w1.x + mv.z) * s1.x);
  r[5] = f32_to_bf16((w1.y + mv.z) * s1.y);
  r[6] = f32_to_bf16((w1.z + mv.w) * s1.z);
  r[7] = f32_to_bf16((w1.w + mv.w) * s1.w);
  *(u16x8*)(wb + idx) = r;
}

// ---- Prep 4: x -> bf16 ----
__global__ void pack_x_k(const float* __restrict__ x, unsigned short* __restrict__ xb) {
  size_t idx = ((size_t)blockIdx.x * 256 + threadIdx.x) * 8;
  float4 v0 = *(const float4*)(x + idx);
  float4 v1 = *(const float4*)(x + idx + 4);
  u16x8 r;
  r[0] = f32_to_bf16(v0.x); r[1] = f32_to_bf16(v0.y);
  r[2] = f32_to_bf16(v0.z); r[3] = f32_to_bf16(v0.w);
  r[4] = f32_to_bf16(v1.x); r[5] = f32_to_bf16(v1.y);
  r[6] = f32_to_bf16(v1.z); r[7] = f32_to_bf16(v1.w);
  *(u16x8*)(xb + idx) = r;
}

// ---- Main GEMM: 8-phase, fence-free phases (compiler fine-grain lgkmcnt),
// CORRECT vmcnt ledger (R8 post-mortem): one STAGE/phase spread evenly,
// stage->gate lead 3-5 phases, VM4@ph4 / VM6@ph8 / VM6-prologue.
//   ph1: buf1-A-h1<-t1 (JIT)  ph3: buf0-B-h0<-t+2  ph4: buf0-B-h1 [VM4]
//   ph5: buf0-A-h0            ph6: buf0-A-h1
//   ph7: buf1-B-h0<-t+3      ph8: buf1-B-h1 + buf1-A-h0 [VM6]
// Ledgers: @ph4 outstanding {pph7:2,pph8:4,ph1:2,ph3:2,ph4:2}=12 -> VM4
// retires pph7,pph8,ph1 = buf1 complete before ph5 reads. @ph8 outstanding
// {ph3..ph8}=14 -> VM6 retires ph3-6 = buf0 complete before next ph1.
// WAR per slot: region's last reader >=1 barrier before stage issue.
// Cross-wave: per-wave VM gate + barrier publishes completion. ----
__global__ void __launch_bounds__(512, 2) gemm_bf16_k(
    const unsigned short* __restrict__ xb,   // [8192][4096]
    const unsigned short* __restrict__ wb,   // [4096][4096]
    float* __restrict__ out) {               // [8192][4096]
  // [buf][op A=0/B=1][half][128*64] = 8 x 16KB = 128KB
  __shared__ short lds[2][2][2][128 * 64];

  const int tid = threadIdx.x;
  const int l   = tid & 63;
  const int wid = tid >> 6;
  const int wm  = wid >> 2;                  // 0..1 -> A half / M rows wm*128
  const int wn  = wid & 3;                   // 0..3 -> N cols wn*64
  const int wnh = wn >> 1;                   // B half

  // XCD-aware bijective swizzle (nwg=512, divisible by 8)
  const int orig = blockIdx.x;
  const int swz  = (orig & 7) * (512 >> 3) + (orig >> 3);
  const int by = swz >> 4;                   // 0..31
  const int bx = swz & 15;                   // 0..15

  const unsigned short* ag = xb + (size_t)(by * BM) * K_TOT;
  const unsigned short* bg = wb + (size_t)(bx * BN) * K_TOT;

  // Staging: half-tile = 128 rows x 64 cols (16KB) = 1024 chunks of 16B;
  // thread handles chunks tid and tid+512. LDS dest linear (chunk c -> c*16B);
  // global source pre-swizzled: kblk_src = (c&7) ^ ((c>>3)&7).
  const int row0 = tid >> 3;
  const int kb0  = (tid & 7) ^ (row0 & 7);
  const int off0 = row0 * K_TOT + kb0 * 8;
  const int off1 = off0 + 64 * K_TOT;
  const int ldst = (tid & ~63) * 8;          // wave-uniform LDS base (shorts)

  // Fragment reads: phys kblk = (kh*4 + lq) ^ (lrow&7)
  const int lrow = l & 15;
  const int lq   = l >> 4;
  const int key  = lrow & 7;
  const int ab0  = lrow * 64 + ((lq) ^ key) * 8;        // kh=0
  const int ab1  = lrow * 64 + ((4 + lq) ^ key) * 8;    // kh=1

  s16x8 aA[4][2], bB[4][2];
  f32x4 acc[8][4] = {};

#define STAGE(buf, op, h, t) { \
    short* d = &lds[buf][op][h][0] + ldst; \
    const unsigned short* s = ((op) ? bg : ag) + (size_t)(h) * 128 * K_TOT + (size_t)(t) * BK; \
    gload_lds16(d, s + off0); \
    gload_lds16(d + 4096, s + off1); }
#define DSA(buf, mh) { const short* p = &lds[buf][0][wm][0]; \
    _Pragma("unroll") for (int mm = 0; mm < 4; ++mm) { \
      aA[mm][0] = *(const s16x8*)(p + ((mh) * 4 + mm) * 1024 + ab0); \
      aA[mm][1] = *(const s16x8*)(p + ((mh) * 4 + mm) * 1024 + ab1); } }
#define DSB(buf, nh) { const short* p = &lds[buf][1][wnh][0] + (wn & 1) * 4096; \
    _Pragma("unroll") for (int nn = 0; nn < 2; ++nn) { \
      bB[(nh) * 2 + nn][0] = *(const s16x8*)(p + ((nh) * 2 + nn) * 1024 + ab0); \
      bB[(nh) * 2 + nn][1] = *(const s16x8*)(p + ((nh) * 2 + nn) * 1024 + ab1); } }
#define MMQ(mh, nh) { __builtin_amdgcn_s_setprio(1); \
    _Pragma("unroll") for (int mm = 0; mm < 4; ++mm) \
      _Pragma("unroll") for (int nn = 0; nn < 2; ++nn) \
        _Pragma("unroll") for (int kh = 0; kh < 2; ++kh) \
          acc[(mh) * 4 + mm][(nh) * 2 + nn] = __builtin_amdgcn_mfma_f32_16x16x32_bf16( \
              aA[mm][kh], bB[(nh) * 2 + nn][kh], acc[(mh) * 4 + mm][(nh) * 2 + nn], 0, 0, 0); \
    __builtin_amdgcn_s_setprio(0); }
#define BARm()  asm volatile("s_barrier" ::: "memory")
#define VM6()   asm volatile("s_waitcnt vmcnt(6)" ::: "memory")
#define VM4()   asm volatile("s_waitcnt vmcnt(4)" ::: "memory")
#define VM0()   asm volatile("s_waitcnt vmcnt(0)" ::: "memory")

  // prologue: tile0 (8 loads) + tile1 partial {B-h0, B-h1, A-h0} (6 loads).
  // VM6 retires exactly tile0's 8; leaves the 6 tile-1 loads = steady-state
  // "prev ph7(2) + prev ph8(4)" inventory.
  STAGE(0, 0, 0, 0); STAGE(0, 0, 1, 0); STAGE(0, 1, 0, 0); STAGE(0, 1, 1, 0);
  STAGE(1, 1, 0, 1); STAGE(1, 1, 1, 1); STAGE(1, 0, 0, 1);
  VM6(); BARm();                             // buf0 complete; 6 tile-1 loads in flight

  #pragma unroll 1
  for (int i = 0; i < NIT - 1; ++i) {
    const int t1 = 2 * i + 1;                // buf1's current tile (completed at ph4)
    const int t2 = t1 + 1;                   // buf0's next tile
    const int t3 = t1 + 2;                   // buf1's next tile
    // ph1: buf0 quad(0,0); JIT-stage buf1-A-h1 <- t1 (gated at ph4)
    DSA(0, 0); DSB(0, 0); STAGE(1, 0, 1, t1);
    MMQ(0, 0); BARm();
    // ph2: buf0 quad(0,1)  [last reader of buf0-B]
    DSB(0, 1);
    MMQ(0, 1); BARm();
    // ph3: buf0 quad(1,0) [last reader of buf0-A]; stage buf0-B'-h0
    DSA(0, 1); STAGE(0, 1, 0, t2);
    MMQ(1, 0); BARm();
    // ph4: buf0 quad(1,1); stage buf0-B'-h1; GATE buf1 (VM4)
    STAGE(0, 1, 1, t2);
    MMQ(1, 1); VM4(); BARm();
    // ph5: buf1 quad(0,0); stage buf0-A'-h0
    DSA(1, 0); DSB(1, 0); STAGE(0, 0, 0, t2);
    MMQ(0, 0); BARm();
    // ph6: buf1 quad(0,1) [last reader of buf1-B]; stage buf0-A'-h1
    DSB(1, 1); STAGE(0, 0, 1, t2);
    MMQ(0, 1); BARm();
    // ph7: buf1 quad(1,0) [last reader of buf1-A]; stage buf1-B'-h0
    DSA(1, 1); STAGE(1, 1, 0, t3);
    MMQ(1, 0); BARm();
    // ph8: buf1 quad(1,1); stage buf1-B'-h1 + buf1-A'-h0; GATE buf0 (VM6)
    STAGE(1, 1, 1, t3); STAGE(1, 0, 0, t3);
    MMQ(1, 1); VM6(); BARm();
  }

  // peeled last iter (buf0=tile 62, buf1=tile 63): only ph1's JIT stage
  DSA(0, 0); DSB(0, 0); STAGE(1, 0, 1, 63);
  MMQ(0, 0); BARm();
  DSB(0, 1);
  MMQ(0, 1); BARm();
  DSA(0, 1);
  MMQ(1, 0); BARm();
  MMQ(1, 1); VM0(); BARm();                  // tile 63 fully landed
  DSA(1, 0); DSB(1, 0);
  MMQ(0, 0); BARm();
  DSB(1, 1);
  MMQ(0, 1); BARm();
  DSA(1, 1);
  MMQ(1, 0); BARm();
  MMQ(1, 1);

#undef STAGE
#undef DSA
#undef DSB
#undef MMQ

  // C/D layout (verified R1-R7): col = lane&15, row = (lane>>4)*4 + reg
  const int row0o = by * BM + wm * 128 + lq * 4;
  const int col0o = bx * BN + wn * 64 + lrow;
  #pragma unroll
  for (int m = 0; m < 8; ++m)
    #pragma unroll
    for (int n = 0; n < 4; ++n) {
      #pragma unroll
      for (int j = 0; j < 4; ++j)
        out[(size_t)(row0o + m * 16 + j) * N_TOT + col0o + n * 16] = acc[m][n][j];
    }
}

// ---- Fallback fp32 GEMM (only if ws too small for bf16 copies) ----
__global__ void gemm_fb_k(const float* __restrict__ x, const float* __restrict__ weight,
                          const float* __restrict__ mora, const float* __restrict__ scale,
                          float* __restrict__ out) {
  __shared__ float As[64][17];
  __shared__ float Bs[64][17];
  int t = threadIdx.x;
  int bx = blockIdx.x, by = blockIdx.y;
  int tr = t >> 4, tc = t & 15;
  float c[4][4] = {};
  for (int kt = 0; kt < K_TOT; kt += 16) {
    #pragma unroll
    for (int r = 0; r < 4; ++r) {
      int idx = r * 256 + t;
      int row = idx >> 4, col = idx & 15;
      As[row][col] = x[(size_t)(by * 64 + row) * K_TOT + kt + col];
      int o = bx * 64 + row, d = kt + col;
      Bs[row][col] = (weight[(size_t)o * K_TOT + d] + mora[(size_t)(o >> 1) * 2048 + (d >> 1)]) * scale[d];
    }
    __syncthreads();
    #pragma unroll
    for (int k = 0; k < 16; ++k) {
      float av[4], bv[4];
      #pragma unroll
      for (int i = 0; i < 4; ++i) av[i] = As[tr * 4 + i][k];
      #pragma unroll
      for (int j = 0; j < 4; ++j) bv[j] = Bs[tc * 4 + j][k];
      #pragma unroll
      for (int i = 0; i < 4; ++i)
        #pragma unroll
        for (int j = 0; j < 4; ++j)
          c[i][j] = fmaf(av[i], bv[j], c[i][j]);
    }
    __syncthreads();
  }
  #pragma unroll
  for (int i = 0; i < 4; ++i)
    #pragma unroll
    for (int j = 0; j < 4; ++j)
      out[(size_t)(by * 64 + tr * 4 + i) * N_TOT + bx * 64 + tc * 4 + j] = c[i][j];
}

extern "C" void kernel_launch(void* const* d_in, const int* in_sizes, int n_in,
                              void* d_out, int out_size, void* d_ws, size_t ws_size,
                              hipStream_t stream) {
  const float* x      = (const float*)d_in[0];   // (4,2048,4096) f32
  const float* weight = (const float*)d_in[1];   // (4096,4096)   f32
  const float* mora   = (const float*)d_in[2];   // (2048,2048)   f32
  const float* dora   = (const float*)d_in[3];   // (1,4096)      f32
  float* out = (float*)d_out;                    // (4,2048,4096) f32

  char* ws = (char*)d_ws;
  float* partials = (float*)ws;                         // 512 KB
  float* scale    = (float*)(ws + (512 << 10));         // 16 KB
  const size_t OFF_W = (size_t)1 << 20;
  unsigned short* wbuf = (unsigned short*)(ws + OFF_W);                              // 32 MB
  unsigned short* xbuf = (unsigned short*)(ws + OFF_W + (size_t)N_TOT * K_TOT * 2);  // 64 MB
  const size_t NEED = OFF_W + (size_t)N_TOT * K_TOT * 2 + (size_t)M_TOT * K_TOT * 2;

  dim3 b256(256);
  colnorm_partial_k<<<dim3(16, 32), b256, 0, stream>>>(weight, mora, partials);
  scale_k<<<16, b256, 0, stream>>>(partials, dora, scale);

  if (ws_size >= NEED) {
    pack_w_k<<<(N_TOT * K_TOT) / (256 * 8), b256, 0, stream>>>(weight, mora, scale, wbuf);
    pack_x_k<<<(M_TOT * K_TOT) / (256 * 8), b256, 0, stream>>>(x, xbuf);
    gemm_bf16_k<<<(M_TOT / BM) * (N_TOT / BN), 512, 0, stream>>>(xbuf, wbuf, out);
  } else {
    gemm_fb_k<<<dim3(N_TOT / 64, M_TOT / 64), b256, 0, stream>>>(x, weight, mora, scale, out);
  }
}

// Round 11
// 298.435 us; speedup vs baseline: 1.0524x; 1.0155x over previous
//
#include <hip/hip_runtime.h>
#include <stdint.h>

#define M_TOT 8192
#define N_TOT 4096
#define K_TOT 4096
#define BM 256
#define BN 256
#define BK 64
#define NIT (K_TOT / (2 * BK))   // 32 iters, 2 K-tiles each

typedef short  s16x8 __attribute__((ext_vector_type(8)));
typedef unsigned short u16x8 __attribute__((ext_vector_type(8)));
typedef float  f32x4 __attribute__((ext_vector_type(4)));

__device__ __forceinline__ unsigned short f32_to_bf16(float f) {
  union { float f; unsigned u; } v; v.f = f;
  unsigned r = v.u + 0x7FFFu + ((v.u >> 16) & 1u);   // RNE
  return (unsigned short)(r >> 16);
}

__device__ __forceinline__ void gload_lds16(void* lds, const void* g) {
  __builtin_amdgcn_global_load_lds(
      (const __attribute__((address_space(1))) unsigned int*)g,
      (__attribute__((address_space(3))) unsigned int*)lds,
      16, 0, 0);
}

// ---- Prep 1: partial column sums of squares of (weight + tiled mora) ----
__global__ void colnorm_partial_k(const float* __restrict__ weight,
                                  const float* __restrict__ mora,
                                  float* __restrict__ partials) {
  int d = blockIdx.x * 256 + threadIdx.x;
  int o0 = blockIdx.y * 128;
  float s = 0.f;
  #pragma unroll 4
  for (int o = o0; o < o0 + 128; ++o) {
    float w = weight[(size_t)o * K_TOT + d] + mora[(size_t)(o >> 1) * 2048 + (d >> 1)];
    s = fmaf(w, w, s);
  }
  partials[blockIdx.y * K_TOT + d] = s;
}

// ---- Prep 2: scale[d] = dora_mag[d] / sqrt(sum) ----
__global__ void scale_k(const float* __restrict__ partials,
                        const float* __restrict__ dora_mag,
                        float* __restrict__ scale) {
  int d = blockIdx.x * 256 + threadIdx.x;
  float s = 0.f;
  #pragma unroll
  for (int c = 0; c < 32; ++c) s += partials[c * K_TOT + d];
  scale[d] = dora_mag[d] / sqrtf(s);
}

// ---- Prep 3: w_bf16[o][d] = bf16((weight + mora_tiled) * scale[d]) ----
__global__ void pack_w_k(const float* __restrict__ weight,
                         const float* __restrict__ mora,
                         const float* __restrict__ scale,
                         unsigned short* __restrict__ wb) {
  size_t idx = ((size_t)blockIdx.x * 256 + threadIdx.x) * 8;
  int o = (int)(idx >> 12);
  int d = (int)(idx & (K_TOT - 1));
  float4 w0 = *(const float4*)(weight + idx);
  float4 w1 = *(const float4*)(weight + idx + 4);
  float4 mv = *(const float4*)(mora + (size_t)(o >> 1) * 2048 + (d >> 1));
  float4 s0 = *(const float4*)(scale + d);
  float4 s1 = *(const float4*)(scale + d + 4);
  u16x8 r;
  r[0] = f32_to_bf16((w0.x + mv.x) * s0.x);
  r[1] = f32_to_bf16((w0.y + mv.x) * s0.y);
  r[2] = f32_to_bf16((w0.z + mv.y) * s0.z);
  r[3] = f32_to_bf16((w0.w + mv.y) * s0.w);
  r[4] = f32_to_bf16((w1.x + mv.z) * s1.x);
  r[5] = f32_to_bf16((w1.y + mv.z) * s1.y);
  r[6] = f32_to_bf16((w1.z + mv.w) * s1.z);
  r[7] = f32_to_bf16((w1.w + mv.w) * s1.w);
  *(u16x8*)(wb + idx) = r;
}

// ---- Prep 4: x -> bf16 ----
__global__ void pack_x_k(const float* __restrict__ x, unsigned short* __restrict__ xb) {
  size_t idx = ((size_t)blockIdx.x * 256 + threadIdx.x) * 8;
  float4 v0 = *(const float4*)(x + idx);
  float4 v1 = *(const float4*)(x + idx + 4);
  u16x8 r;
  r[0] = f32_to_bf16(v0.x); r[1] = f32_to_bf16(v0.y);
  r[2] = f32_to_bf16(v0.z); r[3] = f32_to_bf16(v0.w);
  r[4] = f32_to_bf16(v1.x); r[5] = f32_to_bf16(v1.y);
  r[6] = f32_to_bf16(v1.z); r[7] = f32_to_bf16(v1.w);
  *(u16x8*)(xb + idx) = r;
}

// ---- Main GEMM: R10 rotation, RACE-FIXED (R11): reads of freshly-gated
// buffers moved AFTER the gate barrier (gate = own-wave vmcnt + s_barrier;
// vmcnt alone is per-wave and cannot order other waves' staging loads).
// Read-issue schedule (6/8 quadrants one-phase-ahead, 2 same-phase at gates):
//   ph1: q1(A00+B00, SAME-phase) + q2(B01)   ph2: q3(A01)
//   ph5: q5(A10+B10, SAME-phase) + q6(B11)   ph6: q7(A11)
// Stages (R9 ledger): ph1 JIT buf1-A-h1(t1); ph3/ph4 buf0-B'(t2);
// ph5/ph6 buf0-A'(t2); ph7 buf1-B'h0(t3); ph8 buf1-B'h1+A'h0(t3).
// Gates: VM4@ph4+BAR before ph5 reads (retires prev-ph7/8+ph1 = buf1 tile);
// VM6@ph8+BAR before ph1' reads (retires ph3-6 = buf0-next tile).
// Inventory 6->14 steady, never below 4. ----
__global__ void __launch_bounds__(512, 2) gemm_bf16_k(
    const unsigned short* __restrict__ xb,   // [8192][4096]
    const unsigned short* __restrict__ wb,   // [4096][4096]
    float* __restrict__ out) {               // [8192][4096]
  // [buf][op A=0/B=1][half][128*64] = 8 x 16KB = 128KB
  __shared__ short lds[2][2][2][128 * 64];

  const int tid = threadIdx.x;
  const int l   = tid & 63;
  const int wid = tid >> 6;
  const int wm  = wid >> 2;                  // 0..1 -> A half / M rows wm*128
  const int wn  = wid & 3;                   // 0..3 -> N cols wn*64
  const int wnh = wn >> 1;                   // B half

  // XCD-aware bijective swizzle (nwg=512, divisible by 8)
  const int orig = blockIdx.x;
  const int swz  = (orig & 7) * (512 >> 3) + (orig >> 3);
  const int by = swz >> 4;                   // 0..31
  const int bx = swz & 15;                   // 0..15

  const unsigned short* ag = xb + (size_t)(by * BM) * K_TOT;
  const unsigned short* bg = wb + (size_t)(bx * BN) * K_TOT;

  // Staging: half-tile = 128x64 (16KB) = 1024 chunks of 16B; thread does
  // chunks tid, tid+512. LDS dest linear; global source pre-swizzled:
  // kblk_src = (c&7) ^ ((c>>3)&7).
  const int row0 = tid >> 3;
  const int kb0  = (tid & 7) ^ (row0 & 7);
  const int off0 = row0 * K_TOT + kb0 * 8;
  const int off1 = off0 + 64 * K_TOT;
  const int ldst = (tid & ~63) * 8;          // wave-uniform LDS base (shorts)

  // Fragment reads: phys kblk = (kh*4 + lq) ^ (lrow&7)
  const int lrow = l & 15;
  const int lq   = l >> 4;
  const int key  = lrow & 7;
  const int ab0  = lrow * 64 + ((lq) ^ key) * 8;        // kh=0
  const int ab1  = lrow * 64 + ((4 + lq) ^ key) * 8;    // kh=1

  s16x8 aA[4][2], bB[4][2];
  f32x4 acc[8][4] = {};

#define STAGE(buf, op, h, t) { \
    short* d = &lds[buf][op][h][0] + ldst; \
    const unsigned short* s = ((op) ? bg : ag) + (size_t)(h) * 128 * K_TOT + (size_t)(t) * BK; \
    gload_lds16(d, s + off0); \
    gload_lds16(d + 4096, s + off1); }
#define DSA(buf, mh) { const short* p = &lds[buf][0][wm][0]; \
    _Pragma("unroll") for (int mm = 0; mm < 4; ++mm) { \
      aA[mm][0] = *(const s16x8*)(p + ((mh) * 4 + mm) * 1024 + ab0); \
      aA[mm][1] = *(const s16x8*)(p + ((mh) * 4 + mm) * 1024 + ab1); } }
#define DSB(buf, nh) { const short* p = &lds[buf][1][wnh][0] + (wn & 1) * 4096; \
    _Pragma("unroll") for (int nn = 0; nn < 2; ++nn) { \
      bB[(nh) * 2 + nn][0] = *(const s16x8*)(p + ((nh) * 2 + nn) * 1024 + ab0); \
      bB[(nh) * 2 + nn][1] = *(const s16x8*)(p + ((nh) * 2 + nn) * 1024 + ab1); } }
#define MMQ(mh, nh) { __builtin_amdgcn_s_setprio(1); \
    _Pragma("unroll") for (int mm = 0; mm < 4; ++mm) \
      _Pragma("unroll") for (int nn = 0; nn < 2; ++nn) \
        _Pragma("unroll") for (int kh = 0; kh < 2; ++kh) \
          acc[(mh) * 4 + mm][(nh) * 2 + nn] = __builtin_amdgcn_mfma_f32_16x16x32_bf16( \
              aA[mm][kh], bB[(nh) * 2 + nn][kh], acc[(mh) * 4 + mm][(nh) * 2 + nn], 0, 0, 0); \
    __builtin_amdgcn_s_setprio(0); }
#define BARm()  asm volatile("s_barrier" ::: "memory")
#define VM6()   asm volatile("s_waitcnt vmcnt(6)" ::: "memory")
#define VM4()   asm volatile("s_waitcnt vmcnt(4)" ::: "memory")
#define VM0()   asm volatile("s_waitcnt vmcnt(0)" ::: "memory")

  // prologue: tile0 (8 loads) + tile1 partial {B-h0,B-h1,A-h0} (6 loads);
  // VM6 retires exactly tile0's 8; barrier publishes across waves.
  STAGE(0, 0, 0, 0); STAGE(0, 0, 1, 0); STAGE(0, 1, 0, 0); STAGE(0, 1, 1, 0);
  STAGE(1, 1, 0, 1); STAGE(1, 1, 1, 1); STAGE(1, 0, 0, 1);
  VM6(); BARm();

  #pragma unroll 1
  for (int i = 0; i < NIT - 1; ++i) {
    const int t1 = 2 * i + 1;                // buf1's current tile
    const int t2 = t1 + 1;                   // buf0's next tile
    const int t3 = t1 + 2;                   // buf1's next tile
    // ph1: read q1 (post-gate-barrier, same-phase) + q2 (B01, one ahead);
    //      MMQ q1; JIT stage buf1-A-h1 <- t1
    DSA(0, 0); DSB(0, 0); MMQ(0, 0); DSB(0, 1); STAGE(1, 0, 1, t1); BARm();
    // ph2: MMQ q2 (frags from ph1); read q3 (A01)
    MMQ(0, 1); DSA(0, 1); BARm();
    // ph3: MMQ q3; stage buf0-B'-h0
    MMQ(1, 0); STAGE(0, 1, 0, t2); BARm();
    // ph4: MMQ q4 (aA ph2, bB ph1); stage buf0-B'-h1; GATE buf1 (VM4+BAR)
    MMQ(1, 1); STAGE(0, 1, 1, t2); VM4(); BARm();
    // ph5: read q5 (post-gate-barrier, same-phase) + q6 (B11); MMQ q5;
    //      stage buf0-A'-h0
    DSA(1, 0); DSB(1, 0); MMQ(0, 0); DSB(1, 1); STAGE(0, 0, 0, t2); BARm();
    // ph6: MMQ q6; read q7 (A11); stage buf0-A'-h1
    MMQ(0, 1); DSA(1, 1); STAGE(0, 0, 1, t2); BARm();
    // ph7: MMQ q7; stage buf1-B'-h0 <- t3
    MMQ(1, 0); STAGE(1, 1, 0, t3); BARm();
    // ph8: MMQ q8; stage buf1-B'-h1 + buf1-A'-h0; GATE buf0-next (VM6+BAR)
    MMQ(1, 1); STAGE(1, 1, 1, t3); STAGE(1, 0, 0, t3); VM6(); BARm();
  }

  // peeled last iter (buf0=tile 62, buf1=tile 63): stages dropped except
  // ph1's JIT for t63-A-h1; VM0 gate at ph4 (drains all 8 outstanding).
  DSA(0, 0); DSB(0, 0); MMQ(0, 0); DSB(0, 1); STAGE(1, 0, 1, 63); BARm();
  MMQ(0, 1); DSA(0, 1); BARm();
  MMQ(1, 0); BARm();
  MMQ(1, 1); VM0(); BARm();                  // tile 63 fully landed + published
  DSA(1, 0); DSB(1, 0); MMQ(0, 0); DSB(1, 1); BARm();
  MMQ(0, 1); DSA(1, 1); BARm();
  MMQ(1, 0); BARm();
  MMQ(1, 1);

#undef STAGE
#undef DSA
#undef DSB
#undef MMQ

  // C/D layout (verified R1-R9): col = lane&15, row = (lane>>4)*4 + reg
  const int row0o = by * BM + wm * 128 + lq * 4;
  const int col0o = bx * BN + wn * 64 + lrow;
  #pragma unroll
  for (int m = 0; m < 8; ++m)
    #pragma unroll
    for (int n = 0; n < 4; ++n) {
      #pragma unroll
      for (int j = 0; j < 4; ++j)
        out[(size_t)(row0o + m * 16 + j) * N_TOT + col0o + n * 16] = acc[m][n][j];
    }
}

// ---- Fallback fp32 GEMM (only if ws too small for bf16 copies) ----
__global__ void gemm_fb_k(const float* __restrict__ x, const float* __restrict__ weight,
                          const float* __restrict__ mora, const float* __restrict__ scale,
                          float* __restrict__ out) {
  __shared__ float As[64][17];
  __shared__ float Bs[64][17];
  int t = threadIdx.x;
  int bx = blockIdx.x, by = blockIdx.y;
  int tr = t >> 4, tc = t & 15;
  float c[4][4] = {};
  for (int kt = 0; kt < K_TOT; kt += 16) {
    #pragma unroll
    for (int r = 0; r < 4; ++r) {
      int idx = r * 256 + t;
      int row = idx >> 4, col = idx & 15;
      As[row][col] = x[(size_t)(by * 64 + row) * K_TOT + kt + col];
      int o = bx * 64 + row, d = kt + col;
      Bs[row][col] = (weight[(size_t)o * K_TOT + d] + mora[(size_t)(o >> 1) * 2048 + (d >> 1)]) * scale[d];
    }
    __syncthreads();
    #pragma unroll
    for (int k = 0; k < 16; ++k) {
      float av[4], bv[4];
      #pragma unroll
      for (int i = 0; i < 4; ++i) av[i] = As[tr * 4 + i][k];
      #pragma unroll
      for (int j = 0; j < 4; ++j) bv[j] = Bs[tc * 4 + j][k];
      #pragma unroll
      for (int i = 0; i < 4; ++i)
        #pragma unroll
        for (int j = 0; j < 4; ++j)
          c[i][j] = fmaf(av[i], bv[j], c[i][j]);
    }
    __syncthreads();
  }
  #pragma unroll
  for (int i = 0; i < 4; ++i)
    #pragma unroll
    for (int j = 0; j < 4; ++j)
      out[(size_t)(by * 64 + tr * 4 + i) * N_TOT + bx * 64 + tc * 4 + j] = c[i][j];
}

extern "C" void kernel_launch(void* const* d_in, const int* in_sizes, int n_in,
                              void* d_out, int out_size, void* d_ws, size_t ws_size,
                              hipStream_t stream) {
  const float* x      = (const float*)d_in[0];   // (4,2048,4096) f32
  const float* weight = (const float*)d_in[1];   // (4096,4096)   f32
  const float* mora   = (const float*)d_in[2];   // (2048,2048)   f32
  const float* dora   = (const float*)d_in[3];   // (1,4096)      f32
  float* out = (float*)d_out;                    // (4,2048,4096) f32

  char* ws = (char*)d_ws;
  float* partials = (float*)ws;                         // 512 KB
  float* scale    = (float*)(ws + (512 << 10));         // 16 KB
  const size_t OFF_W = (size_t)1 << 20;
  unsigned short* wbuf = (unsigned short*)(ws + OFF_W);                              // 32 MB
  unsigned short* xbuf = (unsigned short*)(ws + OFF_W + (size_t)N_TOT * K_TOT * 2);  // 64 MB
  const size_t NEED = OFF_W + (size_t)N_TOT * K_TOT * 2 + (size_t)M_TOT * K_TOT * 2;

  dim3 b256(256);
  colnorm_partial_k<<<dim3(16, 32), b256, 0, stream>>>(weight, mora, partials);
  scale_k<<<16, b256, 0, stream>>>(partials, dora, scale);

  if (ws_size >= NEED) {
    pack_w_k<<<(N_TOT * K_TOT) / (256 * 8), b256, 0, stream>>>(weight, mora, scale, wbuf);
    pack_x_k<<<(M_TOT * K_TOT) / (256 * 8), b256, 0, stream>>>(x, xbuf);
    gemm_bf16_k<<<(M_TOT / BM) * (N_TOT / BN), 512, 0, stream>>>(xbuf, wbuf, out);
  } else {
    gemm_fb_k<<<dim3(N_TOT / 64, M_TOT / 64), b256, 0, stream>>>(x, weight, mora, scale, out);
  }
}